// Round 1
// baseline (391.857 us; speedup 1.0000x reference)
//
#include <hip/hip_runtime.h>

// Problem: L1 loss between CIE-Lab L channels of two (64,3,512,512) f32 images.
// HW = 512*512 = 262144, B = 64, pixels = 16,777,216.
// Memory-bound: 402.6 MB read -> ~64 us floor at 6.3 TB/s.

#define HW        262144
#define HW4       65536      // HW/4 (float4 units per channel plane)
#define CHW4      196608     // 3*HW/4 (float4 units per image)
#define NPIX      16777216   // 64*HW
#define NGRP      4194304    // NPIX/4 (float4 pixel groups)

__device__ __forceinline__ float fast_log2(float x) {
#if __has_builtin(__builtin_amdgcn_logf)
    return __builtin_amdgcn_logf(x);      // v_log_f32 (log2)
#else
    return __log2f(x);
#endif
}
__device__ __forceinline__ float fast_exp2(float x) {
#if __has_builtin(__builtin_amdgcn_exp2f)
    return __builtin_amdgcn_exp2f(x);     // v_exp_f32 (2^x)
#else
    return exp2f(x);
#endif
}

// inverse sRGB companding: x in [-1,1] raw -> linear-light value
__device__ __forceinline__ float srgb_expand(float x) {
    float s  = fmaf(x, 0.5f, 0.5f);                         // to [0,1]
    // hi branch: ((s+0.055)/1.055)^2.4  via exp2(2.4*log2(a)), a >= 0.052 (safe)
    float a  = (s + 0.055f) * (1.0f / 1.055f);
    float hi = fast_exp2(2.4f * fast_log2(a));
    float lo = s * (1.0f / 12.92f);
    return (s > 0.04045f) ? hi : lo;
}

// Lab f(Y) from raw rgb (without the 116*f-16 affine; folded into caller)
__device__ __forceinline__ float lab_f(float r, float g, float b) {
    float lr = srgb_expand(r);
    float lg = srgb_expand(g);
    float lb = srgb_expand(b);
    float Y  = fmaf(0.2126729f, lr, fmaf(0.7151522f, lg, 0.0721750f * lb));
    // cbrt via exp2(log2(Y)/3); Y<=eps path selected away (log2(0)=-inf -> exp2 -> 0, harmless)
    float cb = fast_exp2(0.333333333333f * fast_log2(Y));
    float lin = fmaf(7.787f, Y, 16.0f / 116.0f);
    return (Y > 0.008856f) ? cb : lin;
}

__global__ void zero_out_kernel(float* out) {
    if (threadIdx.x == 0) out[0] = 0.0f;
}

__global__ __launch_bounds__(256) void lum_loss_kernel(
        const float* __restrict__ gen,
        const float* __restrict__ tgt,
        float* __restrict__ out) {
    const float4* gp = (const float4*)gen;
    const float4* tp = (const float4*)tgt;

    float acc = 0.0f;
    int tid = blockIdx.x * blockDim.x + threadIdx.x;
    int nth = gridDim.x * blockDim.x;

    for (int grp = tid; grp < NGRP; grp += nth) {
        int b    = grp >> 16;          // batch index  (grp / HW4)
        int i    = grp & 65535;        // float4 index within channel plane
        int base = b * CHW4 + i;

        float4 gr = gp[base];
        float4 gg = gp[base + HW4];
        float4 gb = gp[base + 2 * HW4];
        float4 tr = tp[base];
        float4 tg = tp[base + HW4];
        float4 tb = tp[base + 2 * HW4];

        acc += fabsf(lab_f(gr.x, gg.x, gb.x) - lab_f(tr.x, tg.x, tb.x));
        acc += fabsf(lab_f(gr.y, gg.y, gb.y) - lab_f(tr.y, tg.y, tb.y));
        acc += fabsf(lab_f(gr.z, gg.z, gb.z) - lab_f(tr.z, tg.z, tb.z));
        acc += fabsf(lab_f(gr.w, gg.w, gb.w) - lab_f(tr.w, tg.w, tb.w));
    }
    // L = 116*f - 16  =>  |L_g - L_t| = 116*|f_g - f_t|; fold the 116 here once
    acc *= 116.0f;

    // wave64 reduce
    #pragma unroll
    for (int off = 32; off > 0; off >>= 1)
        acc += __shfl_down(acc, off, 64);

    __shared__ float smem[4];
    int lane = threadIdx.x & 63;
    int wave = threadIdx.x >> 6;
    if (lane == 0) smem[wave] = acc;
    __syncthreads();

    if (threadIdx.x == 0) {
        float s = smem[0] + smem[1] + smem[2] + smem[3];
        atomicAdd(out, s * (1.0f / (float)NPIX));
    }
}

extern "C" void kernel_launch(void* const* d_in, const int* in_sizes, int n_in,
                              void* d_out, int out_size, void* d_ws, size_t ws_size,
                              hipStream_t stream) {
    const float* gen = (const float*)d_in[0];
    const float* tgt = (const float*)d_in[1];
    float* out = (float*)d_out;

    zero_out_kernel<<<1, 64, 0, stream>>>(out);
    // 2048 blocks x 256 thr = 524288 threads; 8 float4-groups (32 pixels) each
    lum_loss_kernel<<<2048, 256, 0, stream>>>(gen, tgt, out);
}

// Round 2
// 391.458 us; speedup vs baseline: 1.0010x; 1.0010x over previous
//
#include <hip/hip_runtime.h>

// L1 loss between CIE-Lab L channels of two (64,3,512,512) f32 images.
// HW = 512*512 = 262144, B = 64, pixels = 16,777,216.
// R1 analysis: latency-bound (VALUBusy 27%, BW 19%, same dur when L3-resident).
// Fix: full unroll (8 float4-groups/thread), 4 accumulators, VGPR cap 128
// via __launch_bounds__(256,4) to expose ILP across transcendental chains.

#define HW4       65536      // HW/4 (float4 units per channel plane)
#define CHW4      196608     // 3*HW/4 (float4 units per image)
#define NPIX      16777216   // 64*HW
#define NGRP      4194304    // NPIX/4 (float4 pixel groups)
#define NTH       524288     // 2048 blocks * 256 threads

__device__ __forceinline__ float fast_log2(float x) {
#if __has_builtin(__builtin_amdgcn_logf)
    return __builtin_amdgcn_logf(x);      // v_log_f32 (log2)
#else
    return __log2f(x);
#endif
}
__device__ __forceinline__ float fast_exp2(float x) {
#if __has_builtin(__builtin_amdgcn_exp2f)
    return __builtin_amdgcn_exp2f(x);     // v_exp_f32 (2^x)
#else
    return exp2f(x);
#endif
}

// inverse sRGB companding on raw x in [-1,1] (s = (x+1)/2 folded into FMAs):
//   a  = (s+0.055)/1.055 = fma(x, 0.47393364f, 0.52606636f)
//   lo = s/12.92         = fma(x, 0.03869969f, 0.03869969f)
//   hi = a^2.4 = exp2(2.4*log2(a));  select on s>0.04045 <=> x>-0.9191
__device__ __forceinline__ float srgb_expand(float x) {
    float a  = fmaf(x, 0.47393364f, 0.52606636f);
    float hi = fast_exp2(2.4f * fast_log2(a));
    float lo = fmaf(x, 0.03869969f, 0.03869969f);
    return (x > -0.9191f) ? hi : lo;
}

// Lab f(Y) from raw rgb (116*f-16 affine folded into caller: |dL| = 116*|df|)
__device__ __forceinline__ float lab_f(float r, float g, float b) {
    float lr = srgb_expand(r);
    float lg = srgb_expand(g);
    float lb = srgb_expand(b);
    float Y  = fmaf(0.2126729f, lr, fmaf(0.7151522f, lg, 0.0721750f * lb));
    float cb = fast_exp2(0.333333333333f * fast_log2(Y));
    float lin = fmaf(7.787f, Y, 16.0f / 116.0f);
    return (Y > 0.008856f) ? cb : lin;
}

__device__ __forceinline__ float group_absdiff(
        float4 gr, float4 gg, float4 gb,
        float4 tr, float4 tg, float4 tb) {
    float s;
    s  = fabsf(lab_f(gr.x, gg.x, gb.x) - lab_f(tr.x, tg.x, tb.x));
    s += fabsf(lab_f(gr.y, gg.y, gb.y) - lab_f(tr.y, tg.y, tb.y));
    s += fabsf(lab_f(gr.z, gg.z, gb.z) - lab_f(tr.z, tg.z, tb.z));
    s += fabsf(lab_f(gr.w, gg.w, gb.w) - lab_f(tr.w, tg.w, tb.w));
    return s;
}

__global__ void zero_out_kernel(float* out) {
    if (threadIdx.x == 0) out[0] = 0.0f;
}

__global__ __launch_bounds__(256, 4) void lum_loss_kernel(
        const float* __restrict__ gen,
        const float* __restrict__ tgt,
        float* __restrict__ out) {
    const float4* gp = (const float4*)gen;
    const float4* tp = (const float4*)tgt;

    int tid = blockIdx.x * 256 + threadIdx.x;

    float acc[4] = {0.0f, 0.0f, 0.0f, 0.0f};

    // NGRP / NTH == 8 exactly: fully unrolled, no bounds checks.
    #pragma unroll
    for (int j = 0; j < 8; ++j) {
        int grp  = tid + j * NTH;
        int b    = grp >> 16;          // grp / HW4
        int i    = grp & 65535;        // grp % HW4
        int base = b * CHW4 + i;

        float4 gr = gp[base];
        float4 gg = gp[base + HW4];
        float4 gb = gp[base + 2 * HW4];
        float4 tr = tp[base];
        float4 tg = tp[base + HW4];
        float4 tb = tp[base + 2 * HW4];

        acc[j & 3] += group_absdiff(gr, gg, gb, tr, tg, tb);
    }

    float a = ((acc[0] + acc[1]) + (acc[2] + acc[3])) * 116.0f;

    // wave64 reduce
    #pragma unroll
    for (int off = 32; off > 0; off >>= 1)
        a += __shfl_down(a, off, 64);

    __shared__ float smem[4];
    int lane = threadIdx.x & 63;
    int wave = threadIdx.x >> 6;
    if (lane == 0) smem[wave] = a;
    __syncthreads();

    if (threadIdx.x == 0) {
        float s = smem[0] + smem[1] + smem[2] + smem[3];
        atomicAdd(out, s * (1.0f / (float)NPIX));
    }
}

extern "C" void kernel_launch(void* const* d_in, const int* in_sizes, int n_in,
                              void* d_out, int out_size, void* d_ws, size_t ws_size,
                              hipStream_t stream) {
    const float* gen = (const float*)d_in[0];
    const float* tgt = (const float*)d_in[1];
    float* out = (float*)d_out;

    zero_out_kernel<<<1, 64, 0, stream>>>(out);
    lum_loss_kernel<<<2048, 256, 0, stream>>>(gen, tgt, out);
}

// Round 3
// 386.704 us; speedup vs baseline: 1.0133x; 1.0123x over previous
//
#include <hip/hip_runtime.h>

// L1 loss between CIE-Lab L channels of two (64,3,512,512) f32 images.
// R2 analysis: MLP-bound. VGPR=28 proved the compiler serialized the 6 loads
// per loop iteration (load->waitcnt->use), ~5000 cyc/iter vs ~300 cyc issue.
// L3-resident replays ran at identical 134us -> latency-bound, not BW-bound.
// Fix: loop-free body. Each thread = 2 adjacent float4-groups, 12 independent
// straight-line global_load_dwordx4 -> 12-deep MLP/wave. 4096 blk x 512 thr.

#define HW4   65536      // HW/4 float4 units per channel plane
#define CHW4  196608     // 3*HW/4 float4 units per image
#define NPIX  16777216

__device__ __forceinline__ float fast_log2(float x) {
#if __has_builtin(__builtin_amdgcn_logf)
    return __builtin_amdgcn_logf(x);      // v_log_f32 (log2)
#else
    return __log2f(x);
#endif
}
__device__ __forceinline__ float fast_exp2(float x) {
#if __has_builtin(__builtin_amdgcn_exp2f)
    return __builtin_amdgcn_exp2f(x);     // v_exp_f32 (2^x)
#else
    return exp2f(x);
#endif
}

// inverse sRGB companding on raw x in [-1,1], s=(x+1)/2 folded into FMAs:
//   a  = (s+0.055)/1.055 = fma(x, 0.47393364, 0.52606636)
//   lo = s/12.92         = fma(x, 0.03869969, 0.03869969)
//   hi = a^2.4 = exp2(2.4*log2(a));  select on s>0.04045 <=> x>-0.9191
__device__ __forceinline__ float srgb_expand(float x) {
    float a  = fmaf(x, 0.47393364f, 0.52606636f);
    float hi = fast_exp2(2.4f * fast_log2(a));
    float lo = fmaf(x, 0.03869969f, 0.03869969f);
    return (x > -0.9191f) ? hi : lo;
}

// Lab f(Y); the 116*f-16 affine is folded into caller (|dL| = 116*|df|)
__device__ __forceinline__ float lab_f(float r, float g, float b) {
    float lr = srgb_expand(r);
    float lg = srgb_expand(g);
    float lb = srgb_expand(b);
    float Y  = fmaf(0.2126729f, lr, fmaf(0.7151522f, lg, 0.0721750f * lb));
    float cb = fast_exp2(0.333333333333f * fast_log2(Y));
    float lin = fmaf(7.787f, Y, 16.0f / 116.0f);
    return (Y > 0.008856f) ? cb : lin;
}

__device__ __forceinline__ float group_absdiff(
        float4 gr, float4 gg, float4 gb,
        float4 tr, float4 tg, float4 tb) {
    float s;
    s  = fabsf(lab_f(gr.x, gg.x, gb.x) - lab_f(tr.x, tg.x, tb.x));
    s += fabsf(lab_f(gr.y, gg.y, gb.y) - lab_f(tr.y, tg.y, tb.y));
    s += fabsf(lab_f(gr.z, gg.z, gb.z) - lab_f(tr.z, tg.z, tb.z));
    s += fabsf(lab_f(gr.w, gg.w, gb.w) - lab_f(tr.w, tg.w, tb.w));
    return s;
}

__global__ void zero_out_kernel(float* out) {
    if (threadIdx.x == 0) out[0] = 0.0f;
}

__global__ __launch_bounds__(512, 4) void lum_loss_kernel(
        const float* __restrict__ gen,
        const float* __restrict__ tgt,
        float* __restrict__ out) {
    const float4* gp = (const float4*)gen;
    const float4* tp = (const float4*)tgt;

    // thread t handles adjacent float4-groups 2t and 2t+1 (same batch image:
    // group index within plane is even, +1 never crosses HW4 boundary).
    int t    = blockIdx.x * 512 + threadIdx.x;     // 0 .. 2M-1
    int g0   = t << 1;
    int b    = g0 >> 16;                           // g0 / HW4
    int i    = g0 & 65535;                         // g0 % HW4
    int base = b * CHW4 + i;

    // 12 independent loads, straight-line: compiler clusters them -> 12-deep
    // MLP per wave, progressive vmcnt(N) before first use.
    float4 gr0 = gp[base];
    float4 gr1 = gp[base + 1];
    float4 gg0 = gp[base + HW4];
    float4 gg1 = gp[base + HW4 + 1];
    float4 gb0 = gp[base + 2 * HW4];
    float4 gb1 = gp[base + 2 * HW4 + 1];
    float4 tr0 = tp[base];
    float4 tr1 = tp[base + 1];
    float4 tg0 = tp[base + HW4];
    float4 tg1 = tp[base + HW4 + 1];
    float4 tb0 = tp[base + 2 * HW4];
    float4 tb1 = tp[base + 2 * HW4 + 1];

    float a = group_absdiff(gr0, gg0, gb0, tr0, tg0, tb0)
            + group_absdiff(gr1, gg1, gb1, tr1, tg1, tb1);
    a *= 116.0f;

    // wave64 reduce
    #pragma unroll
    for (int off = 32; off > 0; off >>= 1)
        a += __shfl_down(a, off, 64);

    __shared__ float smem[8];
    int lane = threadIdx.x & 63;
    int wave = threadIdx.x >> 6;
    if (lane == 0) smem[wave] = a;
    __syncthreads();

    if (threadIdx.x == 0) {
        float s = ((smem[0] + smem[1]) + (smem[2] + smem[3]))
                + ((smem[4] + smem[5]) + (smem[6] + smem[7]));
        atomicAdd(out, s * (1.0f / (float)NPIX));
    }
}

extern "C" void kernel_launch(void* const* d_in, const int* in_sizes, int n_in,
                              void* d_out, int out_size, void* d_ws, size_t ws_size,
                              hipStream_t stream) {
    const float* gen = (const float*)d_in[0];
    const float* tgt = (const float*)d_in[1];
    float* out = (float*)d_out;

    zero_out_kernel<<<1, 64, 0, stream>>>(out);
    // 2,097,152 threads, 2 float4-groups (8 pixels) each = 16,777,216 pixels
    lum_loss_kernel<<<4096, 512, 0, stream>>>(gen, tgt, out);
}